// Round 1
// baseline (891.892 us; speedup 1.0000x reference)
//
#include <hip/hip_runtime.h>
#include <math.h>

#define NB 8
#define P_TOTAL 13343
#define NCLS 80
#define KTOP 1000
#define CHUNK 4096
#define NCHUNK 4
#define NCAND (NCHUNK * 1024)
#define D_SCORE_THR 0.05
#define D_IOU_THR 0.6

// ---------------- device helpers ----------------

__device__ __forceinline__ double sig64(double x) {
    // stable logistic in f64; <=1-2 ulp from any standard f64 expit -> ordering-safe
    if (x >= 0.0) {
        double e = exp(-x);
        return 1.0 / (1.0 + e);
    } else {
        double e = exp(x);
        return e / (1.0 + e);
    }
}

// Bitonic sort, descending by (key desc, idx asc). n power of two.
__device__ void bitonic_desc(double* sk, int* sv, int n, int tid, int nthr) {
    for (int k2 = 2; k2 <= n; k2 <<= 1) {
        for (int j = k2 >> 1; j > 0; j >>= 1) {
            for (int t = tid; t < (n >> 1); t += nthr) {
                int i = ((t & ~(j - 1)) << 1) | (t & (j - 1));
                int l = i | j;
                double ki = sk[i], kl = sk[l];
                int vi = sv[i], vl = sv[l];
                bool prec = (ki > kl) || (ki == kl && vi < vl);
                bool desc = ((i & k2) == 0);
                if (prec != desc) {
                    sk[i] = kl; sk[l] = ki;
                    sv[i] = vl; sv[l] = vi;
                }
            }
            __syncthreads();
        }
    }
}

// ---------------- S0: per-point scores / classes ----------------

__global__ __launch_bounds__(256) void k_scores(
    const float* __restrict__ c0, const float* __restrict__ c1, const float* __restrict__ c2,
    const float* __restrict__ c3, const float* __restrict__ c4,
    const float* __restrict__ n0, const float* __restrict__ n1, const float* __restrict__ n2,
    const float* __restrict__ n3, const float* __restrict__ n4,
    double* __restrict__ scores, int* __restrict__ classes)
{
    int gid = blockIdx.x * blockDim.x + threadIdx.x;
    if (gid >= NB * P_TOTAL) return;
    int b = gid / P_TOTAL;
    int p = gid - b * P_TOTAL;

    int base, hw;
    const float* cls;
    const float* cnt;
    if (p < 10000)      { base = 0;     hw = 10000; cls = c0; cnt = n0; }
    else if (p < 12500) { base = 10000; hw = 2500;  cls = c1; cnt = n1; }
    else if (p < 13125) { base = 12500; hw = 625;   cls = c2; cnt = n2; }
    else if (p < 13294) { base = 13125; hw = 169;   cls = c3; cnt = n3; }
    else                { base = 13294; hw = 49;    cls = c4; cnt = n4; }
    int yx = p - base;

    // argmax over 80 class logits (monotone under sigmoid -> same argmax/max)
    const float* cp = cls + (size_t)b * NCLS * hw + yx;
    float m = -3.4e38f;
    int am = 0;
    for (int c = 0; c < NCLS; ++c) {
        float v = cp[(size_t)c * hw];
        if (v > m) { m = v; am = c; }   // strict '>' keeps FIRST max, matching jnp.argmax
    }
    float cv = cnt[(size_t)b * hw + yx];

    double s = sqrt(sig64((double)m) * sig64((double)cv));
    scores[gid] = s;
    classes[gid] = am + 1;
}

// ---------------- S1: per-chunk sort, keep top 1024 ----------------

__global__ __launch_bounds__(256) void k_chunk_sort(
    const double* __restrict__ scores,
    double* __restrict__ ckeys, int* __restrict__ cidx)
{
    __shared__ double sk[CHUNK];
    __shared__ int sv[CHUNK];
    int b = blockIdx.x / NCHUNK;
    int ch = blockIdx.x - b * NCHUNK;
    int base = ch * CHUNK;
    for (int t = threadIdx.x; t < CHUNK; t += 256) {
        int p = base + t;
        sk[t] = (p < P_TOTAL) ? scores[(size_t)b * P_TOTAL + p] : -1.0; // real scores > 0
        sv[t] = p;
    }
    __syncthreads();
    bitonic_desc(sk, sv, CHUNK, threadIdx.x, 256);
    for (int t = threadIdx.x; t < 1024; t += 256) {
        ckeys[((size_t)b * NCHUNK + ch) * 1024 + t] = sk[t];
        cidx[((size_t)b * NCHUNK + ch) * 1024 + t] = sv[t];
    }
}

// ---------------- S2: final sort of 4096 candidates -> top 1000 ----------------

__global__ __launch_bounds__(256) void k_final_sort(
    const double* __restrict__ ckeys, const int* __restrict__ cidx,
    double* __restrict__ tkeys, int* __restrict__ tidx)
{
    __shared__ double sk[NCAND];
    __shared__ int sv[NCAND];
    int b = blockIdx.x;
    for (int t = threadIdx.x; t < NCAND; t += 256) {
        sk[t] = ckeys[(size_t)b * NCAND + t];
        sv[t] = cidx[(size_t)b * NCAND + t];
    }
    __syncthreads();
    bitonic_desc(sk, sv, NCAND, threadIdx.x, 256);
    for (int t = threadIdx.x; t < KTOP; t += 256) {
        tkeys[(size_t)b * KTOP + t] = sk[t];
        tidx[(size_t)b * KTOP + t] = sv[t];
    }
}

// ---------------- S3: gather boxes, greedy NMS (f64), write outputs ----------------

__global__ __launch_bounds__(256) void k_nms(
    const double* __restrict__ tkeys, const int* __restrict__ tidx,
    const int* __restrict__ classes,
    const float* __restrict__ r0, const float* __restrict__ r1, const float* __restrict__ r2,
    const float* __restrict__ r3, const float* __restrict__ r4,
    float* __restrict__ out)
{
    __shared__ double bx1[KTOP], by1[KTOP], bx2[KTOP], by2[KTOP], ar[KTOP];
    __shared__ int keep[KTOP];
    __shared__ double red[256];

    int b = blockIdx.x;
    int tid = threadIdx.x;

    double obox[4][4];
    double osc[4];
    int ocls[4];
    double lmax = -1e300;

#pragma unroll
    for (int k = 0; k < 4; ++k) {
        int j = tid + k * 256;
        if (j < KTOP) {
            double sc = tkeys[(size_t)b * KTOP + j];
            int idx = tidx[(size_t)b * KTOP + j];
            int base, w, hw, st;
            const float* reg;
            if (idx < 10000)      { base = 0;     w = 100; hw = 10000; st = 8;   reg = r0; }
            else if (idx < 12500) { base = 10000; w = 50;  hw = 2500;  st = 16;  reg = r1; }
            else if (idx < 13125) { base = 12500; w = 25;  hw = 625;   st = 32;  reg = r2; }
            else if (idx < 13294) { base = 13125; w = 13;  hw = 169;   st = 64;  reg = r3; }
            else                  { base = 13294; w = 7;   hw = 49;    st = 128; reg = r4; }
            int yx = idx - base;
            int y = yx / w;
            int x = yx - y * w;
            double sx = (double)(x * st + st / 2);
            double sy = (double)(y * st + st / 2);
            const float* rp = reg + (size_t)b * 4 * hw + yx;
            double g0 = (double)rp[0];
            double g1 = (double)rp[hw];
            double g2 = (double)rp[2 * (size_t)hw];
            double g3 = (double)rp[3 * (size_t)hw];
            double v0 = sx - g0, v1 = sy - g1, v2 = sx + g2, v3 = sy + g3;
            int cv = classes[(size_t)b * P_TOTAL + idx];
            bool valid = (sc >= D_SCORE_THR);

            obox[k][0] = v0; obox[k][1] = v1; obox[k][2] = v2; obox[k][3] = v3;
            osc[k] = sc;
            ocls[k] = cv;
            // max over where(valid, coords, 0.0) -- every entry contributes
            lmax = fmax(lmax, valid ? v0 : 0.0);
            lmax = fmax(lmax, valid ? v1 : 0.0);
            lmax = fmax(lmax, valid ? v2 : 0.0);
            lmax = fmax(lmax, valid ? v3 : 0.0);
            keep[j] = valid ? 1 : 0;
        }
    }
    red[tid] = lmax;
    __syncthreads();
    for (int s = 128; s > 0; s >>= 1) {
        if (tid < s) red[tid] = fmax(red[tid], red[tid + s]);
        __syncthreads();
    }
    double offscale = red[0] + 1.0;
    __syncthreads();

#pragma unroll
    for (int k = 0; k < 4; ++k) {
        int j = tid + k * 256;
        if (j < KTOP) {
            double o = (double)ocls[k] * offscale;
            double x1 = obox[k][0] + o, y1 = obox[k][1] + o;
            double x2 = obox[k][2] + o, y2 = obox[k][3] + o;
            bx1[j] = x1; by1[j] = y1; bx2[j] = x2; by2[j] = y2;
            ar[j] = (x2 - x1 + 1.0) * (y2 - y1 + 1.0);
        }
    }
    __syncthreads();

    // greedy NMS: exact replication of the fori_loop semantics
    for (int i = 0; i < KTOP; ++i) {
        if (keep[i]) {
            double xi1 = bx1[i], yi1 = by1[i], xi2 = bx2[i], yi2 = by2[i], ai = ar[i];
            for (int j = i + 1 + tid; j < KTOP; j += 256) {
                if (keep[j]) {
                    double xmn = fmax(bx1[j], xi1);
                    double ymn = fmax(by1[j], yi1);
                    double xmx = fmin(bx2[j], xi2);
                    double ymx = fmin(by2[j], yi2);
                    double iw = xmx - xmn; if (iw < 0.0) iw = 0.0;
                    double ih = ymx - ymn; if (ih < 0.0) ih = 0.0;
                    double inter = iw * ih;
                    double iou = inter / (ai + ar[j] - inter);
                    if (iou > D_IOU_THR) keep[j] = 0;
                }
            }
            __syncthreads();
        }
    }

    // outputs: scores (8,1000) | classes (8,1000) as float | boxes (8,1000,4)
#pragma unroll
    for (int k = 0; k < 4; ++k) {
        int j = tid + k * 256;
        if (j < KTOP) {
            bool kp = (keep[j] != 0);
            out[(size_t)b * KTOP + j] = kp ? (float)osc[k] : 0.0f;
            out[(size_t)NB * KTOP + (size_t)b * KTOP + j] = kp ? (float)ocls[k] : 0.0f;
            float* ob = out + 2 * (size_t)NB * KTOP + ((size_t)b * KTOP + j) * 4;
            ob[0] = kp ? (float)obox[k][0] : 0.0f;
            ob[1] = kp ? (float)obox[k][1] : 0.0f;
            ob[2] = kp ? (float)obox[k][2] : 0.0f;
            ob[3] = kp ? (float)obox[k][3] : 0.0f;
        }
    }
}

// ---------------- launch ----------------

extern "C" void kernel_launch(void* const* d_in, const int* in_sizes, int n_in,
                              void* d_out, int out_size, void* d_ws, size_t ws_size,
                              hipStream_t stream) {
    const float* cls[5];
    const float* cnt[5];
    const float* reg[5];
    for (int i = 0; i < 5; ++i) {
        cls[i] = (const float*)d_in[i];
        cnt[i] = (const float*)d_in[5 + i];
        reg[i] = (const float*)d_in[10 + i];
    }
    float* out = (float*)d_out;

    // workspace layout (all 8-byte aligned); total ~1.77 MB
    char* ws = (char*)d_ws;
    double* scores = (double*)(ws + 0);                 // NB*P_TOTAL*8   = 853,952
    int*    classes = (int*)(ws + 853952);              // NB*P_TOTAL*4   = 426,976
    double* ckeys  = (double*)(ws + 1280928);           // NB*NCAND*8     = 262,144
    int*    cidx   = (int*)(ws + 1543072);              // NB*NCAND*4     = 131,072
    double* tkeys  = (double*)(ws + 1674144);           // NB*KTOP*8      = 64,000
    int*    tidx   = (int*)(ws + 1738144);              // NB*KTOP*4      = 32,000

    int total = NB * P_TOTAL;
    k_scores<<<(total + 255) / 256, 256, 0, stream>>>(
        cls[0], cls[1], cls[2], cls[3], cls[4],
        cnt[0], cnt[1], cnt[2], cnt[3], cnt[4],
        scores, classes);

    k_chunk_sort<<<NB * NCHUNK, 256, 0, stream>>>(scores, ckeys, cidx);

    k_final_sort<<<NB, 256, 0, stream>>>(ckeys, cidx, tkeys, tidx);

    k_nms<<<NB, 256, 0, stream>>>(tkeys, tidx, classes,
                                  reg[0], reg[1], reg[2], reg[3], reg[4],
                                  out);
}

// Round 2
// 229.279 us; speedup vs baseline: 3.8900x; 3.8900x over previous
//
#include <hip/hip_runtime.h>
#include <math.h>
#include <stdint.h>

#define NB 8
#define P_TOTAL 13343
#define NCLS 80
#define KTOP 1000
#define PPAD 16384
#define CHUNK 4096
#define NPAD 1024
#define D_SCORE_THR 0.05
#define D_IOU_THR 0.6

// ---------------- helpers ----------------

__device__ __forceinline__ double sig64(double x) {
    if (x >= 0.0) {
        double e = exp(-x);
        return 1.0 / (1.0 + e);
    } else {
        double e = exp(x);
        return e / (1.0 + e);
    }
}

// key = score bits (top 50) | (0x3FFF - idx): descending sort => score desc, idx asc
__device__ __forceinline__ uint64_t pack_key(double s, int p) {
    uint64_t b = (uint64_t)__double_as_longlong(s);
    return (b & ~0x3FFFull) | (uint64_t)(0x3FFF - p);
}

// Bitonic sort (descending) on uint64 keys in LDS. n power of two.
__device__ void bitonic_u64(uint64_t* sk, int n, int tid, int nthr) {
    for (int k2 = 2; k2 <= n; k2 <<= 1) {
        for (int j = k2 >> 1; j > 0; j >>= 1) {
            for (int t = tid; t < (n >> 1); t += nthr) {
                int i = ((t & ~(j - 1)) << 1) | (t & (j - 1));
                int l = i | j;
                uint64_t a = sk[i], b = sk[l];
                bool prec = (a > b);
                bool desc = ((i & k2) == 0);
                if (prec != desc) { sk[i] = b; sk[l] = a; }
            }
            __syncthreads();
        }
    }
}

// ---------------- S0: scores/classes -> packed keys ----------------

__global__ __launch_bounds__(256) void k_scores(
    const float* __restrict__ c0, const float* __restrict__ c1, const float* __restrict__ c2,
    const float* __restrict__ c3, const float* __restrict__ c4,
    const float* __restrict__ n0, const float* __restrict__ n1, const float* __restrict__ n2,
    const float* __restrict__ n3, const float* __restrict__ n4,
    uint64_t* __restrict__ packed, int* __restrict__ classes)
{
    int gid = blockIdx.x * 256 + threadIdx.x;
    if (gid >= NB * PPAD) return;
    int b = gid >> 14;
    int p = gid & (PPAD - 1);
    if (p >= P_TOTAL) { packed[gid] = 0; return; }

    int base, hw;
    const float* cls;
    const float* cnt;
    if (p < 10000)      { base = 0;     hw = 10000; cls = c0; cnt = n0; }
    else if (p < 12500) { base = 10000; hw = 2500;  cls = c1; cnt = n1; }
    else if (p < 13125) { base = 12500; hw = 625;   cls = c2; cnt = n2; }
    else if (p < 13294) { base = 13125; hw = 169;   cls = c3; cnt = n3; }
    else                { base = 13294; hw = 49;    cls = c4; cnt = n4; }
    int yx = p - base;

    const float* cp = cls + (size_t)b * NCLS * hw + yx;
    float m = -3.4e38f;
    int am = 0;
    for (int c = 0; c < NCLS; ++c) {
        float v = cp[(size_t)c * hw];
        if (v > m) { m = v; am = c; }   // first max, matches jnp.argmax
    }
    float cv = cnt[(size_t)b * hw + yx];
    double s = sqrt(sig64((double)m) * sig64((double)cv));

    packed[gid] = pack_key(s, p);
    classes[(size_t)b * P_TOTAL + p] = am + 1;
}

// ---------------- S1: per-chunk sort, keep top 1024 ----------------

__global__ __launch_bounds__(512) void k_chunk(
    const uint64_t* __restrict__ packed, uint64_t* __restrict__ ckeys)
{
    __shared__ uint64_t sk[CHUNK];
    int b = blockIdx.x >> 2;
    int ch = blockIdx.x & 3;
    for (int t = threadIdx.x; t < CHUNK; t += 512)
        sk[t] = packed[(size_t)b * PPAD + ch * CHUNK + t];
    __syncthreads();
    bitonic_u64(sk, CHUNK, threadIdx.x, 512);
    for (int t = threadIdx.x; t < 1024; t += 512)
        ckeys[((size_t)b * 4 + ch) * 1024 + t] = sk[t];
}

// ---------------- S2: final sort of 4096 -> top 1024 ----------------

__global__ __launch_bounds__(512) void k_final(
    const uint64_t* __restrict__ ckeys, uint64_t* __restrict__ tkeys)
{
    __shared__ uint64_t sk[CHUNK];
    int b = blockIdx.x;
    for (int t = threadIdx.x; t < CHUNK; t += 512)
        sk[t] = ckeys[(size_t)b * CHUNK + t];
    __syncthreads();
    bitonic_u64(sk, CHUNK, threadIdx.x, 512);
    for (int t = threadIdx.x; t < 1024; t += 512)
        tkeys[(size_t)b * 1024 + t] = sk[t];
}

// ---------------- S3: gather boxes, offsets, keep-init ----------------

__global__ __launch_bounds__(256) void k_prep(
    const uint64_t* __restrict__ tkeys, const int* __restrict__ classes,
    const float* __restrict__ r0, const float* __restrict__ r1, const float* __restrict__ r2,
    const float* __restrict__ r3, const float* __restrict__ r4,
    double* __restrict__ bx1, double* __restrict__ by1,
    double* __restrict__ bx2, double* __restrict__ by2, double* __restrict__ ar,
    float* __restrict__ outs, float* __restrict__ outc, float* __restrict__ outb,
    uint64_t* __restrict__ keepw)
{
    __shared__ double red[256];
    int b = blockIdx.x;
    int tid = threadIdx.x;

    double vx1[4], vy1[4], vx2[4], vy2[4], sc[4];
    int cls_[4];
    double lmax = -1e300;

#pragma unroll
    for (int k = 0; k < 4; ++k) {
        int j = tid + k * 256;
        uint64_t key = tkeys[(size_t)b * 1024 + j];
        int idx = 0x3FFF - (int)(key & 0x3FFF);
        idx = idx < 0 ? 0 : (idx > P_TOTAL - 1 ? P_TOTAL - 1 : idx);
        double s = __longlong_as_double((long long)(key & ~0x3FFFull));

        int base, w, hw, st;
        const float* reg;
        if (idx < 10000)      { base = 0;     w = 100; hw = 10000; st = 8;   reg = r0; }
        else if (idx < 12500) { base = 10000; w = 50;  hw = 2500;  st = 16;  reg = r1; }
        else if (idx < 13125) { base = 12500; w = 25;  hw = 625;   st = 32;  reg = r2; }
        else if (idx < 13294) { base = 13125; w = 13;  hw = 169;   st = 64;  reg = r3; }
        else                  { base = 13294; w = 7;   hw = 49;    st = 128; reg = r4; }
        int yx = idx - base;
        int y = yx / w;
        int x = yx - y * w;
        double sx = (double)(x * st + st / 2);
        double sy = (double)(y * st + st / 2);
        const float* rp = reg + (size_t)b * 4 * hw + yx;
        double x1 = sx - (double)rp[0];
        double y1 = sy - (double)rp[hw];
        double x2 = sx + (double)rp[2 * (size_t)hw];
        double y2 = sy + (double)rp[3 * (size_t)hw];
        int cv = classes[(size_t)b * P_TOTAL + idx];

        bool valid = (j < KTOP) && (s >= D_SCORE_THR);
        if (j < KTOP) {
            lmax = fmax(lmax, valid ? x1 : 0.0);
            lmax = fmax(lmax, valid ? y1 : 0.0);
            lmax = fmax(lmax, valid ? x2 : 0.0);
            lmax = fmax(lmax, valid ? y2 : 0.0);
        }
        vx1[k] = x1; vy1[k] = y1; vx2[k] = x2; vy2[k] = y2;
        sc[k] = s; cls_[k] = cv;

        uint64_t bal = __ballot(valid);
        if ((tid & 63) == 0) keepw[(size_t)b * 16 + (tid >> 6) + 4 * k] = bal;
    }

    red[tid] = lmax;
    __syncthreads();
    for (int s2 = 128; s2 > 0; s2 >>= 1) {
        if (tid < s2) red[tid] = fmax(red[tid], red[tid + s2]);
        __syncthreads();
    }
    double offscale = red[0] + 1.0;
    __syncthreads();

#pragma unroll
    for (int k = 0; k < 4; ++k) {
        int j = tid + k * 256;
        double o = (double)cls_[k] * offscale;
        double ox1 = vx1[k] + o, oy1 = vy1[k] + o;
        double ox2 = vx2[k] + o, oy2 = vy2[k] + o;
        size_t ix = (size_t)b * 1024 + j;
        bx1[ix] = ox1; by1[ix] = oy1; bx2[ix] = ox2; by2[ix] = oy2;
        ar[ix] = (ox2 - ox1 + 1.0) * (oy2 - oy1 + 1.0);
        if (j < KTOP) {
            outs[ix] = (float)sc[k];
            outc[ix] = (float)cls_[k];
            ((float4*)outb)[ix] = make_float4((float)vx1[k], (float)vy1[k],
                                             (float)vx2[k], (float)vy2[k]);
        }
    }
}

// ---------------- S4: suppression mask matrix ----------------

__global__ __launch_bounds__(256) void k_mask(
    const double* __restrict__ bx1, const double* __restrict__ by1,
    const double* __restrict__ bx2, const double* __restrict__ by2,
    const double* __restrict__ ar, uint64_t* __restrict__ M)
{
    __shared__ double lx1[NPAD], ly1[NPAD], lx2[NPAD], ly2[NPAD], lar[NPAD];
    int b = blockIdx.x >> 4;
    int rb = blockIdx.x & 15;
    for (int t = threadIdx.x; t < NPAD; t += 256) {
        size_t ix = (size_t)b * 1024 + t;
        lx1[t] = bx1[ix]; ly1[t] = by1[ix];
        lx2[t] = bx2[ix]; ly2[t] = by2[ix];
        lar[t] = ar[ix];
    }
    __syncthreads();

    int rl = threadIdx.x >> 2;          // 0..63
    int wq = threadIdx.x & 3;
    int r = rb * 64 + rl;
    double rx1 = lx1[r], ry1 = ly1[r], rx2 = lx2[r], ry2 = ly2[r], ra = lar[r];

#pragma unroll
    for (int ww = 0; ww < 4; ++ww) {
        int w = ww * 4 + wq;
        uint64_t bits = 0;
        if (w * 64 + 63 > r) {
            for (int kk = 0; kk < 64; ++kk) {
                int j = w * 64 + kk;
                double xmn = fmax(lx1[j], rx1);
                double ymn = fmax(ly1[j], ry1);
                double xmx = fmin(lx2[j], rx2);
                double ymx = fmin(ly2[j], ry2);
                double iw = xmx - xmn; iw = iw < 0.0 ? 0.0 : iw;
                double ih = ymx - ymn; ih = ih < 0.0 ? 0.0 : ih;
                double inter = iw * ih;
                double iou = inter / (ra + lar[j] - inter);   // f64 div: bit-exact vs ref
                bits |= ((uint64_t)((j > r) && (iou > D_IOU_THR))) << kk;
            }
        }
        M[((size_t)b * 1024 + r) * 16 + w] = bits;
    }
}

// ---------------- S5: sequential bit-scan + output ----------------

#define RING 16

__global__ __launch_bounds__(64) void k_scan(
    const uint64_t* __restrict__ M, const uint64_t* __restrict__ keepw,
    const float* __restrict__ outs, const float* __restrict__ outc,
    const float* __restrict__ outb, float* __restrict__ out)
{
    __shared__ uint64_t kl[16];
    int b = blockIdx.x;
    int lane = threadIdx.x;          // 64 threads = 1 wave
    const uint64_t* Mb = M + (size_t)b * 1024 * 16;

    uint64_t kw = (lane < 16) ? keepw[(size_t)b * 16 + lane] : 0ull;

    uint64_t m[RING];
#pragma unroll
    for (int d = 0; d < RING; ++d)
        m[d] = (lane < 16) ? Mb[(size_t)d * 16 + lane] : 0ull;

    for (int g = 0; g < 1024; g += RING) {
#pragma unroll
        for (int u = 0; u < RING; ++u) {
            int i = g + u;
            int wi = i >> 6;
            int bi = i & 63;
            bool cond = (lane == wi) && ((kw >> bi) & 1ull);
            if (__ballot(cond)) {
                if (lane < 16) kw &= ~m[u];
            }
            int ip = i + RING;
            uint64_t nv = 0ull;
            if (lane < 16 && ip < 1024) nv = Mb[(size_t)ip * 16 + lane];
            m[u] = nv;
        }
    }

    if (lane < 16) kl[lane] = kw;
    __syncthreads();

    for (int j = lane; j < KTOP; j += 64) {
        bool kp = (kl[j >> 6] >> (j & 63)) & 1ull;
        size_t ix = (size_t)b * 1024 + j;
        out[(size_t)b * KTOP + j] = kp ? outs[ix] : 0.0f;
        out[(size_t)NB * KTOP + (size_t)b * KTOP + j] = kp ? outc[ix] : 0.0f;
        float4 bb = kp ? ((const float4*)outb)[ix] : make_float4(0.f, 0.f, 0.f, 0.f);
        ((float4*)(out + 2 * (size_t)NB * KTOP))[(size_t)b * KTOP + j] = bb;
    }
}

// ---------------- launch ----------------

extern "C" void kernel_launch(void* const* d_in, const int* in_sizes, int n_in,
                              void* d_out, int out_size, void* d_ws, size_t ws_size,
                              hipStream_t stream) {
    const float* cls[5];
    const float* cnt[5];
    const float* reg[5];
    for (int i = 0; i < 5; ++i) {
        cls[i] = (const float*)d_in[i];
        cnt[i] = (const float*)d_in[5 + i];
        reg[i] = (const float*)d_in[10 + i];
    }
    float* out = (float*)d_out;

    // ws layout (bytes); M reuses the packed region (dead after k_final)
    char* ws = (char*)d_ws;
    uint64_t* packed  = (uint64_t*)(ws + 0);          // 8*16384*8   = 1,048,576
    int*      classes = (int*)     (ws + 1048576);    // 8*13343*4   =   426,976
    uint64_t* ckeys   = (uint64_t*)(ws + 1475552);    // 8*4096*8    =   262,144
    uint64_t* tkeys   = (uint64_t*)(ws + 1737696);    // 8*1024*8    =    65,536
    double*   bx1     = (double*)  (ws + 1803232);    // 5 * 8*1024*8 =  327,680
    double*   by1     = (double*)  (ws + 1868768);
    double*   bx2     = (double*)  (ws + 1934304);
    double*   by2     = (double*)  (ws + 1999840);
    double*   ar      = (double*)  (ws + 2065376);
    float*    outs    = (float*)   (ws + 2130912);    // 8*1024*4 = 32,768
    float*    outc    = (float*)   (ws + 2163680);    // 32,768
    float*    outb    = (float*)   (ws + 2196448);    // 8*1024*16 = 131,072
    uint64_t* keepw   = (uint64_t*)(ws + 2327520);    // 8*16*8 = 1,024
    uint64_t* M       = (uint64_t*)(ws + 0);          // 8*1024*16*8 = 1,048,576 (reuse)

    k_scores<<<(NB * PPAD) / 256, 256, 0, stream>>>(
        cls[0], cls[1], cls[2], cls[3], cls[4],
        cnt[0], cnt[1], cnt[2], cnt[3], cnt[4],
        packed, classes);

    k_chunk<<<NB * 4, 512, 0, stream>>>(packed, ckeys);

    k_final<<<NB, 512, 0, stream>>>(ckeys, tkeys);

    k_prep<<<NB, 256, 0, stream>>>(tkeys, classes,
                                   reg[0], reg[1], reg[2], reg[3], reg[4],
                                   bx1, by1, bx2, by2, ar,
                                   outs, outc, outb, keepw);

    k_mask<<<NB * 16, 256, 0, stream>>>(bx1, by1, bx2, by2, ar, M);

    k_scan<<<NB, 64, 0, stream>>>(M, keepw, outs, outc, outb, out);
}

// Round 3
// 161.226 us; speedup vs baseline: 5.5319x; 1.4221x over previous
//
#include <hip/hip_runtime.h>
#include <math.h>
#include <stdint.h>

#define NB 8
#define P_TOTAL 13343
#define NCLS 80
#define KTOP 1000
#define PPAD 16384
#define D_SCORE_THR 0.05
#define D_IOU_THR 0.6

// ---------------- helpers ----------------

__device__ __forceinline__ double sig64(double x) {
    if (x >= 0.0) {
        double e = exp(-x);
        return 1.0 / (1.0 + e);
    } else {
        double e = exp(x);
        return e / (1.0 + e);
    }
}

// key = score bits (top 50) | (0x3FFF - idx): descending sort => score desc, idx asc
__device__ __forceinline__ uint64_t pack_key(double s, int p) {
    uint64_t b = (uint64_t)__double_as_longlong(s);
    return (b & ~0x3FFFull) | (uint64_t)(0x3FFF - p);
}

__device__ __forceinline__ uint64_t rl64(uint64_t v, int l) {
    uint32_t lo = (uint32_t)__builtin_amdgcn_readlane((int)(uint32_t)v, l);
    uint32_t hi = (uint32_t)__builtin_amdgcn_readlane((int)(uint32_t)(v >> 32), l);
    return ((uint64_t)hi << 32) | lo;
}

// Bitonic sort (descending) on uint64 keys in LDS. n power of two.
__device__ void bitonic_u64(uint64_t* sk, int n, int tid, int nthr) {
    for (int k2 = 2; k2 <= n; k2 <<= 1) {
        for (int j = k2 >> 1; j > 0; j >>= 1) {
            for (int t = tid; t < (n >> 1); t += nthr) {
                int i = ((t & ~(j - 1)) << 1) | (t & (j - 1));
                int l = i | j;
                uint64_t a = sk[i], b = sk[l];
                bool prec = (a > b);
                bool desc = ((i & k2) == 0);
                if (prec != desc) { sk[i] = b; sk[l] = a; }
            }
            __syncthreads();
        }
    }
}

// ---------------- S0: scores/classes -> packed keys ----------------

__global__ __launch_bounds__(256) void k_scores(
    const float* __restrict__ c0, const float* __restrict__ c1, const float* __restrict__ c2,
    const float* __restrict__ c3, const float* __restrict__ c4,
    const float* __restrict__ n0, const float* __restrict__ n1, const float* __restrict__ n2,
    const float* __restrict__ n3, const float* __restrict__ n4,
    uint64_t* __restrict__ packed, int* __restrict__ classes)
{
    int gid = blockIdx.x * 256 + threadIdx.x;
    if (gid >= NB * PPAD) return;
    int b = gid >> 14;
    int p = gid & (PPAD - 1);
    if (p >= P_TOTAL) { packed[gid] = 0; return; }

    int base, hw;
    const float* cls;
    const float* cnt;
    if (p < 10000)      { base = 0;     hw = 10000; cls = c0; cnt = n0; }
    else if (p < 12500) { base = 10000; hw = 2500;  cls = c1; cnt = n1; }
    else if (p < 13125) { base = 12500; hw = 625;   cls = c2; cnt = n2; }
    else if (p < 13294) { base = 13125; hw = 169;   cls = c3; cnt = n3; }
    else                { base = 13294; hw = 49;    cls = c4; cnt = n4; }
    int yx = p - base;

    const float* cp = cls + (size_t)b * NCLS * hw + yx;
    float m = -3.4e38f;
    int am = 0;
    for (int c = 0; c < NCLS; ++c) {
        float v = cp[(size_t)c * hw];
        if (v > m) { m = v; am = c; }   // first max, matches jnp.argmax
    }
    float cv = cnt[(size_t)b * hw + yx];
    double s = sqrt(sig64((double)m) * sig64((double)cv));

    packed[gid] = pack_key(s, p);
    classes[(size_t)b * P_TOTAL + p] = am + 1;
}

// ---------------- S1: histogram select + single 2048 sort -> top 1024 ----------------

__global__ __launch_bounds__(512) void k_select(
    const uint64_t* __restrict__ packed, uint64_t* __restrict__ tkeys)
{
    __shared__ uint32_t hist[2048];
    __shared__ uint64_t cand[2048];
    __shared__ uint32_t chs[64];
    __shared__ int sB, sC1, sB2, sCnt;
    int b = blockIdx.x;
    int tid = threadIdx.x;
    const uint64_t* pk = packed + (size_t)b * PPAD;

    for (int t = tid; t < 2048; t += 512) hist[t] = 0;
    __syncthreads();

    // pass 1: coarse 2048-bin value histogram
    for (int t = tid; t < PPAD; t += 512) {
        double s = __longlong_as_double((long long)(pk[t] & ~0x3FFFull));
        int bin = (int)(s * 2048.0);
        bin = bin < 0 ? 0 : (bin > 2047 ? 2047 : bin);
        atomicAdd(&hist[bin], 1u);
    }
    __syncthreads();
    if (tid < 64) {
        uint32_t ssum = 0;
        for (int i = 0; i < 32; ++i) ssum += hist[tid * 32 + i];
        chs[tid] = ssum;
    }
    __syncthreads();
    if (tid == 0) {
        int acc = 0, c = 63;
        for (; c > 0; --c) { if (acc + (int)chs[c] >= 1024) break; acc += (int)chs[c]; }
        int bfound = c * 32;
        for (int bb = c * 32 + 31; bb >= c * 32; --bb) {
            if (acc + (int)hist[bb] >= 1024) { bfound = bb; break; }
            acc += (int)hist[bb];
        }
        sB = bfound; sC1 = acc;   // sC1 = count of keys with bin > sB
    }
    __syncthreads();
    int B = sB;
    for (int t = tid; t < 2048; t += 512) hist[t] = 0;   // sB/sC1 read done; hist dead
    __syncthreads();

    // pass 2: refine crossing bin into 2048 sub-bins
    for (int t = tid; t < PPAD; t += 512) {
        double s = __longlong_as_double((long long)(pk[t] & ~0x3FFFull));
        int bin = (int)(s * 2048.0);
        bin = bin < 0 ? 0 : (bin > 2047 ? 2047 : bin);
        if (bin == B) {
            int sub = (int)(s * 4194304.0) - B * 2048;
            sub = sub < 0 ? 0 : (sub > 2047 ? 2047 : sub);
            atomicAdd(&hist[sub], 1u);
        }
    }
    __syncthreads();
    if (tid < 64) {
        uint32_t ssum = 0;
        for (int i = 0; i < 32; ++i) ssum += hist[tid * 32 + i];
        chs[tid] = ssum;
    }
    __syncthreads();
    if (tid == 0) {
        int acc = sC1, c = 63;
        for (; c > 0; --c) { if (acc + (int)chs[c] >= 1024) break; acc += (int)chs[c]; }
        int bfound = c * 32;
        for (int bb = c * 32 + 31; bb >= c * 32; --bb) {
            if (acc + (int)hist[bb] >= 1024) { bfound = bb; break; }
            acc += (int)hist[bb];
        }
        sB2 = bfound;
        sCnt = 0;
    }
    __syncthreads();
    int B2 = sB2;

    // pass 3: compact candidates (superset of true top-1024; sort canonicalizes)
    for (int t = tid; t < PPAD; t += 512) {
        uint64_t key = pk[t];
        double s = __longlong_as_double((long long)(key & ~0x3FFFull));
        int bin = (int)(s * 2048.0);
        bin = bin < 0 ? 0 : (bin > 2047 ? 2047 : bin);
        bool pred = false;
        if (bin > B) pred = true;
        else if (bin == B) {
            int sub = (int)(s * 4194304.0) - B * 2048;
            sub = sub < 0 ? 0 : (sub > 2047 ? 2047 : sub);
            pred = (sub >= B2);
        }
        if (pred) {
            int slot = atomicAdd(&sCnt, 1);
            if (slot < 2048) cand[slot] = key;
        }
    }
    __syncthreads();
    int cnt = sCnt;
    for (int t = tid; t < 2048; t += 512) if (t >= cnt) cand[t] = 0;
    __syncthreads();

    bitonic_u64(cand, 2048, tid, 512);

    for (int t = tid; t < 1024; t += 512)
        tkeys[(size_t)b * 1024 + t] = cand[t];
}

// ---------------- S2: fused box gather + offsets + mask matrix ----------------

__global__ __launch_bounds__(256) void k_boxmask(
    const uint64_t* __restrict__ tkeys, const int* __restrict__ classes,
    const float* __restrict__ r0, const float* __restrict__ r1, const float* __restrict__ r2,
    const float* __restrict__ r3, const float* __restrict__ r4,
    float* __restrict__ outs, float* __restrict__ outc, float* __restrict__ outb,
    uint64_t* __restrict__ keepw,
    uint64_t* __restrict__ M, uint64_t* __restrict__ D)
{
    __shared__ double lx1[1024], ly1[1024], lx2[1024], ly2[1024], lar[1024];
    __shared__ double red[256];
    int bid = blockIdx.x;
    int b = bid >> 4, rb = bid & 15;
    int tid = threadIdx.x;

    double vx1[4], vy1[4], vx2[4], vy2[4], sc[4];
    int cls_[4];
    double lmax = -1e300;

#pragma unroll
    for (int k = 0; k < 4; ++k) {
        int j = tid + k * 256;
        uint64_t key = tkeys[(size_t)b * 1024 + j];
        int idx = 0x3FFF - (int)(key & 0x3FFF);
        idx = idx < 0 ? 0 : (idx > P_TOTAL - 1 ? P_TOTAL - 1 : idx);
        double s = __longlong_as_double((long long)(key & ~0x3FFFull));

        int base, w, hw, st;
        const float* reg;
        if (idx < 10000)      { base = 0;     w = 100; hw = 10000; st = 8;   reg = r0; }
        else if (idx < 12500) { base = 10000; w = 50;  hw = 2500;  st = 16;  reg = r1; }
        else if (idx < 13125) { base = 12500; w = 25;  hw = 625;   st = 32;  reg = r2; }
        else if (idx < 13294) { base = 13125; w = 13;  hw = 169;   st = 64;  reg = r3; }
        else                  { base = 13294; w = 7;   hw = 49;    st = 128; reg = r4; }
        int yx = idx - base;
        int y = yx / w;
        int x = yx - y * w;
        double sx = (double)(x * st + st / 2);
        double sy = (double)(y * st + st / 2);
        const float* rp = reg + (size_t)b * 4 * hw + yx;
        double x1 = sx - (double)rp[0];
        double y1 = sy - (double)rp[hw];
        double x2 = sx + (double)rp[2 * (size_t)hw];
        double y2 = sy + (double)rp[3 * (size_t)hw];
        int cv = classes[(size_t)b * P_TOTAL + idx];

        bool valid = (j < KTOP) && (s >= D_SCORE_THR);
        if (j < KTOP) {
            lmax = fmax(lmax, valid ? x1 : 0.0);
            lmax = fmax(lmax, valid ? y1 : 0.0);
            lmax = fmax(lmax, valid ? x2 : 0.0);
            lmax = fmax(lmax, valid ? y2 : 0.0);
        }
        vx1[k] = x1; vy1[k] = y1; vx2[k] = x2; vy2[k] = y2;
        sc[k] = s; cls_[k] = cv;

        uint64_t bal = __ballot(valid);
        if (rb == 0 && (tid & 63) == 0) keepw[(size_t)b * 16 + (tid >> 6) + 4 * k] = bal;
    }

    red[tid] = lmax;
    __syncthreads();
    for (int s2 = 128; s2 > 0; s2 >>= 1) {
        if (tid < s2) red[tid] = fmax(red[tid], red[tid + s2]);
        __syncthreads();
    }
    double offscale = red[0] + 1.0;
    __syncthreads();

#pragma unroll
    for (int k = 0; k < 4; ++k) {
        int j = tid + k * 256;
        double o = (double)cls_[k] * offscale;
        double ox1 = vx1[k] + o, oy1 = vy1[k] + o;
        double ox2 = vx2[k] + o, oy2 = vy2[k] + o;
        lx1[j] = ox1; ly1[j] = oy1; lx2[j] = ox2; ly2[j] = oy2;
        lar[j] = (ox2 - ox1 + 1.0) * (oy2 - oy1 + 1.0);
        if (rb == 0 && j < KTOP) {
            size_t ix = (size_t)b * 1024 + j;
            outs[ix] = (float)sc[k];
            outc[ix] = (float)cls_[k];
            ((float4*)outb)[ix] = make_float4((float)vx1[k], (float)vy1[k],
                                              (float)vx2[k], (float)vy2[k]);
        }
    }
    __syncthreads();

    int rl = tid >> 2;          // 0..63
    int wq = tid & 3;
    int r = rb * 64 + rl;
    double rx1 = lx1[r], ry1 = ly1[r], rx2 = lx2[r], ry2 = ly2[r], ra = lar[r];

#pragma unroll
    for (int ww = 0; ww < 4; ++ww) {
        int w = ww * 4 + wq;
        uint64_t bits = 0;
        if (w * 64 + 63 > r) {
            for (int kk = 0; kk < 64; ++kk) {
                int j = w * 64 + kk;
                double xmn = fmax(lx1[j], rx1);
                double ymn = fmax(ly1[j], ry1);
                double xmx = fmin(lx2[j], rx2);
                double ymx = fmin(ly2[j], ry2);
                double iw = xmx - xmn; iw = iw < 0.0 ? 0.0 : iw;
                double ih = ymx - ymn; ih = ih < 0.0 ? 0.0 : ih;
                double inter = iw * ih;
                double iou = inter / (ra + lar[j] - inter);   // f64 div: bit-exact vs ref
                bits |= ((uint64_t)((j > r) && (iou > D_IOU_THR))) << kk;
            }
        }
        M[((size_t)b * 1024 + r) * 16 + w] = bits;
        if (w == rb) D[((size_t)b * 16 + rb) * 64 + rl] = bits;
    }
}

// ---------------- S3: group-based keep scan (scalar ffs chain) ----------------

template <int G>
__device__ __forceinline__ void scan_step(
    uint64_t (&cur)[16], uint64_t (&nxt)[16],
    uint64_t& kw, uint64_t dg, const uint64_t* __restrict__ Mb, int kp, int w)
{
    if (G < 15) {
#pragma unroll
        for (int q = 0; q < 16; ++q)
            nxt[q] = Mb[(size_t)((G + 1) * 64 + 4 * q + kp) * 16 + w];
    }
    // intra-group greedy resolution: visits only alive bits
    uint64_t kg = rl64(kw, G);
    uint64_t rem = kg, alive = 0;
    while (rem) {
        int kk = __builtin_ctzll(rem);
        alive |= 1ull << kk;
        rem &= ~rl64(dg, kk);   // dg bits are strictly > kk
        rem &= rem - 1ull;      // clear bit kk
    }
    // apply alive rows' masks to all words (branchless, 4-way k-parallel)
    uint64_t acc = ~0ull;
#pragma unroll
    for (int q = 0; q < 16; ++q) {
        uint64_t t = (alive >> (4 * q + kp)) & 1ull;
        acc &= ~(cur[q] & (0ull - t));
    }
    acc &= __shfl_xor(acc, 16, 64);
    acc &= __shfl_xor(acc, 32, 64);
    kw &= acc;   // word G becomes exactly `alive`; words < G untouched (M has only j>i bits)
}

__global__ __launch_bounds__(64) void k_scan(
    const uint64_t* __restrict__ M, const uint64_t* __restrict__ D,
    const uint64_t* __restrict__ keepw,
    const float* __restrict__ outs, const float* __restrict__ outc,
    const float* __restrict__ outb, float* __restrict__ out)
{
    __shared__ uint64_t kl[16];
    int b = blockIdx.x;
    int lane = threadIdx.x;
    const uint64_t* Mb = M + (size_t)b * 1024 * 16;
    int kp = lane >> 4, w = lane & 15;

    uint64_t kw = keepw[(size_t)b * 16 + w];   // replicated x4 across kp

    uint64_t Dg[16];
#pragma unroll
    for (int g = 0; g < 16; ++g) Dg[g] = D[((size_t)b * 16 + g) * 64 + lane];

    uint64_t mA[16], mB[16];
#pragma unroll
    for (int q = 0; q < 16; ++q) mA[q] = Mb[(size_t)(4 * q + kp) * 16 + w];

    scan_step<0>(mA, mB, kw, Dg[0], Mb, kp, w);
    scan_step<1>(mB, mA, kw, Dg[1], Mb, kp, w);
    scan_step<2>(mA, mB, kw, Dg[2], Mb, kp, w);
    scan_step<3>(mB, mA, kw, Dg[3], Mb, kp, w);
    scan_step<4>(mA, mB, kw, Dg[4], Mb, kp, w);
    scan_step<5>(mB, mA, kw, Dg[5], Mb, kp, w);
    scan_step<6>(mA, mB, kw, Dg[6], Mb, kp, w);
    scan_step<7>(mB, mA, kw, Dg[7], Mb, kp, w);
    scan_step<8>(mA, mB, kw, Dg[8], Mb, kp, w);
    scan_step<9>(mB, mA, kw, Dg[9], Mb, kp, w);
    scan_step<10>(mA, mB, kw, Dg[10], Mb, kp, w);
    scan_step<11>(mB, mA, kw, Dg[11], Mb, kp, w);
    scan_step<12>(mA, mB, kw, Dg[12], Mb, kp, w);
    scan_step<13>(mB, mA, kw, Dg[13], Mb, kp, w);
    scan_step<14>(mA, mB, kw, Dg[14], Mb, kp, w);
    scan_step<15>(mB, mA, kw, Dg[15], Mb, kp, w);

    if (lane < 16) kl[lane] = kw;
    __syncthreads();

    for (int j = lane; j < KTOP; j += 64) {
        bool kp2 = (kl[j >> 6] >> (j & 63)) & 1ull;
        size_t ix = (size_t)b * 1024 + j;
        out[(size_t)b * KTOP + j] = kp2 ? outs[ix] : 0.0f;
        out[(size_t)NB * KTOP + (size_t)b * KTOP + j] = kp2 ? outc[ix] : 0.0f;
        float4 bb = kp2 ? ((const float4*)outb)[ix] : make_float4(0.f, 0.f, 0.f, 0.f);
        ((float4*)(out + 2 * (size_t)NB * KTOP))[(size_t)b * KTOP + j] = bb;
    }
}

// ---------------- launch ----------------

extern "C" void kernel_launch(void* const* d_in, const int* in_sizes, int n_in,
                              void* d_out, int out_size, void* d_ws, size_t ws_size,
                              hipStream_t stream) {
    const float* cls[5];
    const float* cnt[5];
    const float* reg[5];
    for (int i = 0; i < 5; ++i) {
        cls[i] = (const float*)d_in[i];
        cnt[i] = (const float*)d_in[5 + i];
        reg[i] = (const float*)d_in[10 + i];
    }
    float* out = (float*)d_out;

    // ws layout (bytes); M reuses the packed region (packed dead after k_select)
    char* ws = (char*)d_ws;
    uint64_t* packed  = (uint64_t*)(ws + 0);          // 8*16384*8     = 1,048,576
    uint64_t* M       = (uint64_t*)(ws + 0);          // 8*1024*16*8   = 1,048,576 (reuse)
    int*      classes = (int*)     (ws + 1048576);    // 8*13343*4     =   426,976
    uint64_t* tkeys   = (uint64_t*)(ws + 1475552);    // 8*1024*8      =    65,536
    uint64_t* D       = (uint64_t*)(ws + 1541088);    // 8*16*64*8     =    65,536
    uint64_t* keepw   = (uint64_t*)(ws + 1606624);    // 8*16*8        =     1,024
    float*    outs    = (float*)   (ws + 1607648);    // 8*1024*4      =    32,768
    float*    outc    = (float*)   (ws + 1640416);    // 8*1024*4      =    32,768
    float*    outb    = (float*)   (ws + 1673184);    // 8*1024*16     =   131,072

    k_scores<<<(NB * PPAD) / 256, 256, 0, stream>>>(
        cls[0], cls[1], cls[2], cls[3], cls[4],
        cnt[0], cnt[1], cnt[2], cnt[3], cnt[4],
        packed, classes);

    k_select<<<NB, 512, 0, stream>>>(packed, tkeys);

    k_boxmask<<<NB * 16, 256, 0, stream>>>(tkeys, classes,
                                           reg[0], reg[1], reg[2], reg[3], reg[4],
                                           outs, outc, outb, keepw, M, D);

    k_scan<<<NB, 64, 0, stream>>>(M, D, keepw, outs, outc, outb, out);
}